// Round 7
// baseline (162.038 us; speedup 1.0000x reference)
//
#include <hip/hip_runtime.h>

typedef float f2 __attribute__((ext_vector_type(2)));

#define DD 128
#define HH 256
#define WW 256
#define OD 127
#define SLICE_F (HH*WW)
#define NBIN 64
#define CHUNK 4        // layers per d-chunk (32 chunks; last NT=3)
#define PRED_B 9216    // 9 pred rows x 1KB
#define BITS_B 512     // 16 bit-row slots x 32B (9 used)
#define STAGE_B (PRED_B + BITS_B)
#define NBUF 2
#define WS_BITS_OFF 4096

#define VMCNT0() asm volatile("s_waitcnt vmcnt(0)" ::: "memory")

struct Sl { f2 uu2[4]; f2 vv2[4]; f2 ps[4]; };

// ---- pre-pass: pack targets (exact 0.0/1.0 floats) into 1 bit/voxel ----
__global__ __launch_bounds__(256)
void pack_bits(const float* __restrict__ t, unsigned int* __restrict__ bits)
{
    const int tid = blockIdx.x * 256 + threadIdx.x;     // 524288 threads
    const float4* p = (const float4*)(t + ((size_t)tid << 5));
    unsigned int acc = 0;
    #pragma unroll
    for (int i = 0; i < 8; ++i) {
        float4 v = p[i];
        unsigned int n = ((__float_as_uint(v.x) >> 29) & 1u)
                       | (((__float_as_uint(v.y) >> 29) & 1u) << 1)
                       | (((__float_as_uint(v.z) >> 29) & 1u) << 2)
                       | (((__float_as_uint(v.w) >> 29) & 1u) << 3);
        acc |= n << (i * 4);
    }
    bits[tid] = acc;                                     // linear order matches voxels
}

// ---- stage one slice: 9 pred rows (16B loads) + 9 bit rows (4B loads) ----
__device__ __forceinline__ void stage_slice(const float* __restrict__ pB,
                                            const unsigned int* __restrict__ bB,
                                            int slice, char* lb,
                                            int h0, int wv, int lane)
{
    #pragma unroll
    for (int i = 0; i < 3; ++i) {
        const int slot = i * 4 + wv;                     // 0..11, wave-uniform branch
        if (slot < 9) {
            const int grow = min(h0 + slot, HH - 1);
            const float* g = pB + ((size_t)slice << 16) + (grow << 8) + (lane << 2);
            void* l = lb + slot * 1024 + lane * 16;
            __builtin_amdgcn_global_load_lds(
                (const __attribute__((address_space(1))) void*)g,
                (__attribute__((address_space(3))) void*)l, 16, 0, 0);
        } else if (slot < 11) {
            const int half = slot - 9;                   // 0: rows 0-7, 1: rows 8-15
            const int row  = (half << 3) + (lane >> 3);
            const int grow = min(h0 + row, HH - 1);
            const unsigned int* g = bB + (((size_t)slice * HH + grow) << 3) + (lane & 7);
            void* l = lb + PRED_B + half * 256 + lane * 4;
            __builtin_amdgcn_global_load_lds(
                (const __attribute__((address_space(1))) void*)g,
                (__attribute__((address_space(3))) void*)l, 4, 0, 0);
        }
    }
}

__device__ __forceinline__ void make_sl_lds(const char* buf, int wv, int lane, Sl& S)
{
    const float* sp = (const float*)buf;
    const unsigned int* bl = (const unsigned int*)(buf + PRED_B);
    const int ro = ((wv << 1) << 8) + (lane << 2);       // row 2*wv, col lane*4
    const float4 p0 = *(const float4*)(sp + ro);
    const float4 p1 = *(const float4*)(sp + ro + 256);
    const float4 p2 = *(const float4*)(sp + ro + 512);

    float u0x=__expf(p0.x), u0y=__expf(p0.y), u0z=__expf(p0.z), u0w=__expf(p0.w);
    float u1x=__expf(p1.x), u1y=__expf(p1.y), u1z=__expf(p1.z), u1w=__expf(p1.w);
    float u2x=__expf(p2.x), u2y=__expf(p2.y), u2z=__expf(p2.z), u2w=__expf(p2.w);

    f2 uA0 = {u0x,u1x}, uB0 = {u1x,u2x};
    f2 uA1 = {u0y,u1y}, uB1 = {u1y,u2y};
    f2 uA2 = {u0z,u1z}, uB2 = {u1z,u2z};
    f2 uA3 = {u0w,u1w}, uB3 = {u1w,u2w};

    f2 W0 = uA0*uB0, W1 = uA1*uB1, W2 = uA2*uB2, W3 = uA3*uB3;
    f2 Q0 = (uA0+1.f)*(uB0+1.f);
    f2 Q1 = (uA1+1.f)*(uB1+1.f);
    f2 Q2 = (uA2+1.f)*(uB2+1.f);
    f2 Q3 = (uA3+1.f)*(uB3+1.f);
    f2 W4, Q4;
    W4.x = __shfl_down(W0.x, 1); W4.y = __shfl_down(W0.y, 1);
    Q4.x = __shfl_down(Q0.x, 1); Q4.y = __shfl_down(Q0.y, 1);

    S.uu2[0]=W0*W1; S.uu2[1]=W1*W2; S.uu2[2]=W2*W3; S.uu2[3]=W3*W4;
    S.vv2[0]=Q0*Q1; S.vv2[1]=Q1*Q2; S.vv2[2]=Q2*Q3; S.vv2[3]=Q3*Q4;

    // 5-bit windows (cols 4l..4l+4) for the wave's 3 rows; lane63 bit4 garbage -> masked (j==3)
    const int r = wv << 1;
    const int q = lane >> 3;
    const int sh = (lane & 7) << 2;
    unsigned int a0 = bl[r*8 + q],     a1 = bl[r*8 + q + 1];
    unsigned int b0 = bl[(r+1)*8 + q], b1 = bl[(r+1)*8 + q + 1];
    unsigned int c0 = bl[(r+2)*8 + q], c1 = bl[(r+2)*8 + q + 1];
    unsigned int m0 = (unsigned int)(((((unsigned long long)a1) << 32) | a0) >> sh) & 0x1Fu;
    unsigned int m1 = (unsigned int)(((((unsigned long long)b1) << 32) | b0) >> sh) & 0x1Fu;
    unsigned int m2 = (unsigned int)(((((unsigned long long)c1) << 32) | c0) >> sh) & 0x1Fu;
    unsigned int M01 = m0 | (m1 << 8);
    unsigned int M12 = m1 | (m2 << 8);
    #pragma unroll
    for (int j = 0; j < 4; ++j) {
        S.ps[j].x = (float)__popc((M01 >> j) & 0x303u);  // 2x2 pair sum, slice-local
        S.ps[j].y = (float)__popc((M12 >> j) & 0x303u);
    }
}

__device__ __forceinline__ void do_cubes(const Sl& P, const Sl& C,
        const f2 vAll, const f2 v3,
        f2& aFG, f2& aF255, f2& aBG, f2& aBG0, f2& aSFA,
        f2& c255, f2& c0, f2& cMN)
{
    #pragma unroll
    for (int j = 0; j < 4; ++j) {
        f2 E = P.uu2[j] * C.uu2[j];
        f2 Q = P.vv2[j] * C.vv2[j];
        f2 vj = (j == 3) ? v3 : vAll;
        f2 r; r.x = __builtin_amdgcn_rcpf(Q.x); r.y = __builtin_amdgcn_rcpf(Q.y);
        r *= vj;
        f2 fg = E * r;
        f2 pop = P.ps[j] + C.ps[j];      // exact 0..8
        f2 i255, i0, mn;
        i255.x = fmaxf(pop.x - 7.f, 0.f); i255.y = fmaxf(pop.y - 7.f, 0.f);
        i0.x   = fmaxf(1.f - pop.x, 0.f); i0.y   = fmaxf(1.f - pop.y, 0.f);
        mn.x   = 4.f - fabsf(pop.x - 4.f); mn.y = 4.f - fabsf(pop.y - 4.f);
        mn *= vj;
        aFG  += fg;
        aBG  += r;
        aF255 = fg * i255 + aF255;
        aBG0  = r  * i0   + aBG0;
        c255  = i255 * vj + c255;
        c0    = i0   * vj + c0;
        aSFA  = (fg + r) * mn + aSFA;
        cMN  += mn;
    }
}

#define LAYER(SRC, DST, STAGE_OFF, READ_OFF)                                   \
    do {                                                                       \
        VMCNT0();                                                              \
        __builtin_amdgcn_s_barrier();                                          \
        __builtin_amdgcn_sched_barrier(0);                                     \
        if (t + 2 <= NT)                                                       \
            stage_slice(pB, bB, d0 + t + 2, smem + (STAGE_OFF), h0, wv, lane); \
        make_sl_lds(smem + (READ_OFF), wv, lane, DST);                         \
        do_cubes(SRC, DST, vAll, v3, aFG, aF255, aBG, aBG0, aSFA, c255, c0, cMN); \
    } while (0)

// ws: [0..4KB) bins [NBIN][2][8]; [4KB..) target bitmask (2 MB)
__global__ __launch_bounds__(256, 8)
void loss_main(const float* __restrict__ preds,
               const unsigned int* __restrict__ bits,
               float* __restrict__ ws)
{
    __shared__ __align__(16) char smem[NBUF * STAGE_B];   // 19 KB -> 8 blocks/CU

    const int lane = threadIdx.x & 63;
    const int wv   = threadIdx.x >> 6;

    // bijective XCD-chunked swizzle: 2048 blocks, 256 contiguous per XCD
    const int nid = ((blockIdx.x & 7) << 8) + (blockIdx.x >> 3);
    const int x = nid & 31;            // h-slab
    const int y = (nid >> 5) & 31;     // d-chunk
    const int b = nid >> 10;           // batch

    const int h0 = x << 3;
    const int d0 = y << 2;
    const int NT = min(CHUNK, OD - d0);   // 4 (last chunk: 3)

    const float*        pB = preds + (size_t)b * DD * SLICE_F;
    const unsigned int* bB = bits  + (size_t)b * DD * HH * 8;

    const int   myrow = h0 + (wv << 1);
    const float rv1 = (myrow + 1 < HH - 1) ? 1.f : 0.f;
    const float v63 = (lane == 63) ? 0.f : 1.f;
    const f2 vAll = {1.f, rv1};
    const f2 v3   = {v63, v63 * rv1};

    f2 aFG={0,0}, aF255={0,0}, aBG={0,0}, aBG0={0,0}, aSFA={0,0};
    f2 c255={0,0}, c0={0,0}, cMN={0,0};

    stage_slice(pB, bB, d0,     smem,           h0, wv, lane);
    stage_slice(pB, bB, d0 + 1, smem + STAGE_B, h0, wv, lane);
    VMCNT0();
    __builtin_amdgcn_s_barrier();
    __builtin_amdgcn_sched_barrier(0);

    Sl A, B;
    make_sl_lds(smem, wv, lane, A);

    int t = 0;
    for (;;) {
        LAYER(A, B, 0, STAGE_B);
        if (++t >= NT) break;
        LAYER(B, A, STAGE_B, 0);
        if (++t >= NT) break;
    }

    float acc[8] = {aFG.x+aFG.y, aF255.x+aF255.y, c255.x+c255.y,
                    aBG.x+aBG.y, aBG0.x+aBG0.y,   c0.x+c0.y,
                    aSFA.x+aSFA.y, cMN.x+cMN.y};
    #pragma unroll
    for (int i = 0; i < 8; ++i) {
        float v = acc[i];
        #pragma unroll
        for (int off = 32; off > 0; off >>= 1) v += __shfl_xor(v, off);
        acc[i] = v;
    }
    float mine = acc[0];
    mine = (lane == 1) ? acc[1] : mine;
    mine = (lane == 2) ? acc[2] : mine;
    mine = (lane == 3) ? acc[3] : mine;
    mine = (lane == 4) ? acc[4] : mine;
    mine = (lane == 5) ? acc[5] : mine;
    mine = (lane == 6) ? acc[6] : mine;
    mine = (lane == 7) ? acc[7] : mine;
    if (lane < 8) {
        int bin = nid & (NBIN - 1);
        atomicAdd(&ws[(bin * 2 + b) * 8 + lane], mine);
    }
}

__global__ void loss_final(const float* __restrict__ ws, float* __restrict__ out)
{
    __shared__ float s[16];
    const int t = threadIdx.x;
    if (t < 16) {
        float v = 0.f;
        #pragma unroll 4
        for (int x = 0; x < NBIN; ++x) v += ws[x * 16 + t];
        s[t] = v;
    }
    __syncthreads();
    if (t == 0) {
        const float eps = 1e-5f;
        float dice = 0.f;
        #pragma unroll
        for (int b = 0; b < 2; ++b) {
            const float* q = s + b * 8;
            float fg_dice = (2.f*q[1] + eps) / (q[0] + q[2] + eps);
            float bg_dice = (2.f*q[4] + eps) / (q[3] + q[5] + eps);
            float q6 = 0.5f * q[6];          // area = 0.5*min(pop,8-pop)
            float q7 = 0.5f * q[7];
            float ss = q7 - q6;              // sum(surf*area)
            float sf_dice = (2.f*ss + eps) / (ss + q7 + eps);
            dice += fg_dice + bg_dice + sf_dice;
        }
        out[0] = 1.f - dice * (1.f/6.f);
    }
}

extern "C" void kernel_launch(void* const* d_in, const int* in_sizes, int n_in,
                              void* d_out, int out_size, void* d_ws, size_t ws_size,
                              hipStream_t stream)
{
    const float* preds   = (const float*)d_in[0];
    const float* targets = (const float*)d_in[1];
    // d_in[2] power / d_in[3] kernel / d_in[4] area are analytic -- baked in
    float* ws = (float*)d_ws;
    unsigned int* bitsbuf = (unsigned int*)((char*)d_ws + WS_BITS_OFF);  // 2 MB

    hipMemsetAsync(ws, 0, NBIN * 16 * sizeof(float), stream);

    pack_bits<<<2048, 256, 0, stream>>>(targets, bitsbuf);
    loss_main<<<2048, 256, 0, stream>>>(preds, bitsbuf, ws);   // 8 blocks/CU exact
    loss_final<<<1, 64, 0, stream>>>(ws, (float*)d_out);
}

// Round 8
// 51.924 us; speedup vs baseline: 3.1207x; 3.1207x over previous
//
#include <hip/hip_runtime.h>

typedef float f2 __attribute__((ext_vector_type(2)));

#define DD 128
#define HH 256
#define WW 256
#define OD 127
#define SLICE_F (HH*WW)
#define NBIN 64
#define CHUNK 4        // layers per d-chunk (32 chunks; last NT=3)
#define PRED_B 9216    // 9 pred rows x 1KB
#define BITS_B 512     // 16 bit-row slots x 32B (9 used)
#define STAGE_B (PRED_B + BITS_B)
#define NBUF 2
#define WS_BITS_OFF 4096

#define VMCNT0() asm volatile("s_waitcnt vmcnt(0)" ::: "memory")

struct Sl { f2 uu2[4]; f2 vv2[4]; f2 ps[4]; };

// ---- pre-pass: pack targets (exact 0.0/1.0 floats) into 1 bit/voxel ----
__global__ __launch_bounds__(256)
void pack_bits(const float* __restrict__ t, unsigned int* __restrict__ bits)
{
    const int tid = blockIdx.x * 256 + threadIdx.x;     // 524288 threads
    const float4* p = (const float4*)(t + ((size_t)tid << 5));
    unsigned int acc = 0;
    #pragma unroll
    for (int i = 0; i < 8; ++i) {
        float4 v = p[i];
        unsigned int n = ((__float_as_uint(v.x) >> 29) & 1u)
                       | (((__float_as_uint(v.y) >> 29) & 1u) << 1)
                       | (((__float_as_uint(v.z) >> 29) & 1u) << 2)
                       | (((__float_as_uint(v.w) >> 29) & 1u) << 3);
        acc |= n << (i * 4);
    }
    bits[tid] = acc;                                     // linear order matches voxels
}

// ---- stage one slice: 9 pred rows (16B loads) + 9 bit rows (4B loads) ----
__device__ __forceinline__ void stage_slice(const float* __restrict__ pB,
                                            const unsigned int* __restrict__ bB,
                                            int slice, char* lb,
                                            int h0, int wv, int lane)
{
    #pragma unroll
    for (int i = 0; i < 3; ++i) {
        const int slot = i * 4 + wv;                     // 0..11, wave-uniform branch
        if (slot < 9) {
            const int grow = min(h0 + slot, HH - 1);
            const float* g = pB + ((size_t)slice << 16) + (grow << 8) + (lane << 2);
            void* l = lb + slot * 1024 + lane * 16;
            __builtin_amdgcn_global_load_lds(
                (const __attribute__((address_space(1))) void*)g,
                (__attribute__((address_space(3))) void*)l, 16, 0, 0);
        } else if (slot < 11) {
            const int half = slot - 9;                   // 0: rows 0-7, 1: rows 8-15
            const int row  = (half << 3) + (lane >> 3);
            const int grow = min(h0 + row, HH - 1);
            const unsigned int* g = bB + (((size_t)slice * HH + grow) << 3) + (lane & 7);
            void* l = lb + PRED_B + half * 256 + lane * 4;
            __builtin_amdgcn_global_load_lds(
                (const __attribute__((address_space(1))) void*)g,
                (__attribute__((address_space(3))) void*)l, 4, 0, 0);
        }
    }
}

__device__ __forceinline__ void make_sl_lds(const char* buf, int wv, int lane, Sl& S)
{
    const float* sp = (const float*)buf;
    const unsigned int* bl = (const unsigned int*)(buf + PRED_B);
    const int ro = ((wv << 1) << 8) + (lane << 2);       // row 2*wv, col lane*4
    const float4 p0 = *(const float4*)(sp + ro);
    const float4 p1 = *(const float4*)(sp + ro + 256);
    const float4 p2 = *(const float4*)(sp + ro + 512);

    float u0x=__expf(p0.x), u0y=__expf(p0.y), u0z=__expf(p0.z), u0w=__expf(p0.w);
    float u1x=__expf(p1.x), u1y=__expf(p1.y), u1z=__expf(p1.z), u1w=__expf(p1.w);
    float u2x=__expf(p2.x), u2y=__expf(p2.y), u2z=__expf(p2.z), u2w=__expf(p2.w);

    f2 uA0 = {u0x,u1x}, uB0 = {u1x,u2x};
    f2 uA1 = {u0y,u1y}, uB1 = {u1y,u2y};
    f2 uA2 = {u0z,u1z}, uB2 = {u1z,u2z};
    f2 uA3 = {u0w,u1w}, uB3 = {u1w,u2w};

    f2 W0 = uA0*uB0, W1 = uA1*uB1, W2 = uA2*uB2, W3 = uA3*uB3;
    f2 Q0 = (uA0+1.f)*(uB0+1.f);
    f2 Q1 = (uA1+1.f)*(uB1+1.f);
    f2 Q2 = (uA2+1.f)*(uB2+1.f);
    f2 Q3 = (uA3+1.f)*(uB3+1.f);
    f2 W4, Q4;
    W4.x = __shfl_down(W0.x, 1); W4.y = __shfl_down(W0.y, 1);
    Q4.x = __shfl_down(Q0.x, 1); Q4.y = __shfl_down(Q0.y, 1);

    S.uu2[0]=W0*W1; S.uu2[1]=W1*W2; S.uu2[2]=W2*W3; S.uu2[3]=W3*W4;
    S.vv2[0]=Q0*Q1; S.vv2[1]=Q1*Q2; S.vv2[2]=Q2*Q3; S.vv2[3]=Q3*Q4;

    // 5-bit windows (cols 4l..4l+4) for the wave's 3 rows; lane63 bit4 garbage -> masked (j==3)
    const int r = wv << 1;
    const int q = lane >> 3;
    const int sh = (lane & 7) << 2;
    unsigned int a0 = bl[r*8 + q],     a1 = bl[r*8 + q + 1];
    unsigned int b0 = bl[(r+1)*8 + q], b1 = bl[(r+1)*8 + q + 1];
    unsigned int c0 = bl[(r+2)*8 + q], c1 = bl[(r+2)*8 + q + 1];
    unsigned int m0 = (unsigned int)(((((unsigned long long)a1) << 32) | a0) >> sh) & 0x1Fu;
    unsigned int m1 = (unsigned int)(((((unsigned long long)b1) << 32) | b0) >> sh) & 0x1Fu;
    unsigned int m2 = (unsigned int)(((((unsigned long long)c1) << 32) | c0) >> sh) & 0x1Fu;
    unsigned int M01 = m0 | (m1 << 8);
    unsigned int M12 = m1 | (m2 << 8);
    #pragma unroll
    for (int j = 0; j < 4; ++j) {
        S.ps[j].x = (float)__popc((M01 >> j) & 0x303u);  // 2x2 pair sum, slice-local
        S.ps[j].y = (float)__popc((M12 >> j) & 0x303u);
    }
}

__device__ __forceinline__ void do_cubes(const Sl& P, const Sl& C,
        const f2 vAll, const f2 v3,
        f2& aFG, f2& aF255, f2& aBG, f2& aBG0, f2& aSFA,
        f2& c255, f2& c0, f2& cMN)
{
    #pragma unroll
    for (int j = 0; j < 4; ++j) {
        f2 E = P.uu2[j] * C.uu2[j];
        f2 Q = P.vv2[j] * C.vv2[j];
        f2 vj = (j == 3) ? v3 : vAll;
        f2 r; r.x = __builtin_amdgcn_rcpf(Q.x); r.y = __builtin_amdgcn_rcpf(Q.y);
        r *= vj;
        f2 fg = E * r;
        f2 pop = P.ps[j] + C.ps[j];      // exact 0..8
        f2 i255, i0, mn;
        i255.x = fmaxf(pop.x - 7.f, 0.f); i255.y = fmaxf(pop.y - 7.f, 0.f);
        i0.x   = fmaxf(1.f - pop.x, 0.f); i0.y   = fmaxf(1.f - pop.y, 0.f);
        mn.x   = 4.f - fabsf(pop.x - 4.f); mn.y = 4.f - fabsf(pop.y - 4.f);
        mn *= vj;
        aFG  += fg;
        aBG  += r;
        aF255 = fg * i255 + aF255;
        aBG0  = r  * i0   + aBG0;
        c255  = i255 * vj + c255;
        c0    = i0   * vj + c0;
        aSFA  = (fg + r) * mn + aSFA;
        cMN  += mn;
    }
}

#define LAYER(SRC, DST, STAGE_OFF, READ_OFF)                                   \
    do {                                                                       \
        VMCNT0();                                                              \
        __builtin_amdgcn_s_barrier();                                          \
        __builtin_amdgcn_sched_barrier(0);                                     \
        if (t + 2 <= NT)                                                       \
            stage_slice(pB, bB, d0 + t + 2, smem + (STAGE_OFF), h0, wv, lane); \
        make_sl_lds(smem + (READ_OFF), wv, lane, DST);                         \
        do_cubes(SRC, DST, vAll, v3, aFG, aF255, aBG, aBG0, aSFA, c255, c0, cMN); \
    } while (0)

// ws: [0..4KB) bins [NBIN][2][8]; [4KB..) target bitmask (2 MB)
__global__ __launch_bounds__(256, 4)
void loss_main(const float* __restrict__ preds,
               const unsigned int* __restrict__ bits,
               float* __restrict__ ws)
{
    __shared__ __align__(16) char smem[NBUF * STAGE_B];   // 19 KB -> 8 blocks/CU

    const int lane = threadIdx.x & 63;
    const int wv   = threadIdx.x >> 6;

    // bijective XCD-chunked swizzle: 2048 blocks, 256 contiguous per XCD
    const int nid = ((blockIdx.x & 7) << 8) + (blockIdx.x >> 3);
    const int x = nid & 31;            // h-slab
    const int y = (nid >> 5) & 31;     // d-chunk
    const int b = nid >> 10;           // batch

    const int h0 = x << 3;
    const int d0 = y << 2;
    const int NT = min(CHUNK, OD - d0);   // 4 (last chunk: 3)

    const float*        pB = preds + (size_t)b * DD * SLICE_F;
    const unsigned int* bB = bits  + (size_t)b * DD * HH * 8;

    const int   myrow = h0 + (wv << 1);
    const float rv1 = (myrow + 1 < HH - 1) ? 1.f : 0.f;
    const float v63 = (lane == 63) ? 0.f : 1.f;
    const f2 vAll = {1.f, rv1};
    const f2 v3   = {v63, v63 * rv1};

    f2 aFG={0,0}, aF255={0,0}, aBG={0,0}, aBG0={0,0}, aSFA={0,0};
    f2 c255={0,0}, c0={0,0}, cMN={0,0};

    stage_slice(pB, bB, d0,     smem,           h0, wv, lane);
    stage_slice(pB, bB, d0 + 1, smem + STAGE_B, h0, wv, lane);
    VMCNT0();
    __builtin_amdgcn_s_barrier();
    __builtin_amdgcn_sched_barrier(0);

    Sl A, B;
    make_sl_lds(smem, wv, lane, A);

    int t = 0;
    for (;;) {
        LAYER(A, B, 0, STAGE_B);
        if (++t >= NT) break;
        LAYER(B, A, STAGE_B, 0);
        if (++t >= NT) break;
    }

    float acc[8] = {aFG.x+aFG.y, aF255.x+aF255.y, c255.x+c255.y,
                    aBG.x+aBG.y, aBG0.x+aBG0.y,   c0.x+c0.y,
                    aSFA.x+aSFA.y, cMN.x+cMN.y};
    #pragma unroll
    for (int i = 0; i < 8; ++i) {
        float v = acc[i];
        #pragma unroll
        for (int off = 32; off > 0; off >>= 1) v += __shfl_xor(v, off);
        acc[i] = v;
    }
    float mine = acc[0];
    mine = (lane == 1) ? acc[1] : mine;
    mine = (lane == 2) ? acc[2] : mine;
    mine = (lane == 3) ? acc[3] : mine;
    mine = (lane == 4) ? acc[4] : mine;
    mine = (lane == 5) ? acc[5] : mine;
    mine = (lane == 6) ? acc[6] : mine;
    mine = (lane == 7) ? acc[7] : mine;
    if (lane < 8) {
        int bin = nid & (NBIN - 1);
        atomicAdd(&ws[(bin * 2 + b) * 8 + lane], mine);
    }
}

__global__ void loss_final(const float* __restrict__ ws, float* __restrict__ out)
{
    __shared__ float s[16];
    const int t = threadIdx.x;
    if (t < 16) {
        float v = 0.f;
        #pragma unroll 4
        for (int x = 0; x < NBIN; ++x) v += ws[x * 16 + t];
        s[t] = v;
    }
    __syncthreads();
    if (t == 0) {
        const float eps = 1e-5f;
        float dice = 0.f;
        #pragma unroll
        for (int b = 0; b < 2; ++b) {
            const float* q = s + b * 8;
            float fg_dice = (2.f*q[1] + eps) / (q[0] + q[2] + eps);
            float bg_dice = (2.f*q[4] + eps) / (q[3] + q[5] + eps);
            float q6 = 0.5f * q[6];          // area = 0.5*min(pop,8-pop)
            float q7 = 0.5f * q[7];
            float ss = q7 - q6;              // sum(surf*area)
            float sf_dice = (2.f*ss + eps) / (ss + q7 + eps);
            dice += fg_dice + bg_dice + sf_dice;
        }
        out[0] = 1.f - dice * (1.f/6.f);
    }
}

extern "C" void kernel_launch(void* const* d_in, const int* in_sizes, int n_in,
                              void* d_out, int out_size, void* d_ws, size_t ws_size,
                              hipStream_t stream)
{
    const float* preds   = (const float*)d_in[0];
    const float* targets = (const float*)d_in[1];
    // d_in[2] power / d_in[3] kernel / d_in[4] area are analytic -- baked in
    float* ws = (float*)d_ws;
    unsigned int* bitsbuf = (unsigned int*)((char*)d_ws + WS_BITS_OFF);  // 2 MB

    hipMemsetAsync(ws, 0, NBIN * 16 * sizeof(float), stream);

    pack_bits<<<2048, 256, 0, stream>>>(targets, bitsbuf);
    loss_main<<<2048, 256, 0, stream>>>(preds, bitsbuf, ws);   // 8 blocks/CU exact
    loss_final<<<1, 64, 0, stream>>>(ws, (float*)d_out);
}

// Round 9
// 47.523 us; speedup vs baseline: 3.4097x; 1.0926x over previous
//
#include <hip/hip_runtime.h>

typedef float f2 __attribute__((ext_vector_type(2)));

#define DD 128
#define HH 256
#define WW 256
#define OD 127
#define SLICE_F (HH*WW)
#define CHUNK 8
#define ROW_B 1024
#define SLOT_B 8192      // 8 pred rows
#define NBUF 3

#define VMCNT0() asm volatile("s_waitcnt vmcnt(0)" ::: "memory")
// steady-state wait: stage(t+1)+tregs(t+1) landed; stage(t+2)+tregs(t+2) stay in flight
#define WAITP() do { if (wv == 3) asm volatile("s_waitcnt vmcnt(6)" ::: "memory"); \
                     else         asm volatile("s_waitcnt vmcnt(5)" ::: "memory"); } while (0)

struct Sl { f2 uu2[4]; f2 vv2[4]; f2 ps[4]; };

// stage 8 pred rows of one slice into an LDS slot: 2 global_load_lds per wave
__device__ __forceinline__ void stage_slice(const float* __restrict__ pB, int s,
                                            char* smem, int slot,
                                            int h0, int wv, int lane)
{
    #pragma unroll
    for (int i = 0; i < 2; ++i) {
        const int row = (wv << 1) + i;
        const float* g = pB + ((size_t)s << 16) + ((size_t)(h0 + row) << 8) + (lane << 2);
        void* l = smem + slot * SLOT_B + row * ROW_B + lane * 16;
        __builtin_amdgcn_global_load_lds(
            (const __attribute__((address_space(1))) void*)g,
            (__attribute__((address_space(3))) void*)l, 16, 0, 0);
    }
}

// register prefetch: 3 target rows (all waves) + pred row 8 (wave 3 only)
__device__ __forceinline__ void load_tregs(const float* __restrict__ tB,
                                           const float* __restrict__ pB, int s,
                                           int h0, int wv, int lane,
                                           float4& t0, float4& t1, float4& t2, float4& p8)
{
    const int r0 = h0 + (wv << 1);
    const size_t base = ((size_t)s << 16) + (lane << 2);
    t0 = *(const float4*)(tB + base + ((size_t)r0 << 8));
    t1 = *(const float4*)(tB + base + ((size_t)(r0 + 1) << 8));
    const int r2 = min(r0 + 2, HH - 1);
    t2 = *(const float4*)(tB + base + ((size_t)r2 << 8));
    if (wv == 3) {
        const int r8 = min(h0 + 8, HH - 1);
        p8 = *(const float4*)(pB + base + ((size_t)r8 << 8));
    }
}

__device__ __forceinline__ void make_sl(const char* buf, int wv, int lane,
                                        float4 t0, float4 t1, float4 t2, float4 p8,
                                        Sl& S)
{
    const float* sp = (const float*)buf;
    const int ro = ((wv << 1) << 8) + (lane << 2);
    const float4 p0 = *(const float4*)(sp + ro);
    const float4 p1 = *(const float4*)(sp + ro + 256);
    float4 p2;
    if (wv < 3) p2 = *(const float4*)(sp + ro + 512);
    else        p2 = p8;                      // row 8 via register prefetch

    float u0x=__expf(p0.x), u0y=__expf(p0.y), u0z=__expf(p0.z), u0w=__expf(p0.w);
    float u1x=__expf(p1.x), u1y=__expf(p1.y), u1z=__expf(p1.z), u1w=__expf(p1.w);
    float u2x=__expf(p2.x), u2y=__expf(p2.y), u2z=__expf(p2.z), u2w=__expf(p2.w);

    f2 uA0 = {u0x,u1x}, uB0 = {u1x,u2x};
    f2 uA1 = {u0y,u1y}, uB1 = {u1y,u2y};
    f2 uA2 = {u0z,u1z}, uB2 = {u1z,u2z};
    f2 uA3 = {u0w,u1w}, uB3 = {u1w,u2w};

    f2 W0 = uA0*uB0, W1 = uA1*uB1, W2 = uA2*uB2, W3 = uA3*uB3;
    f2 Q0 = (uA0+1.f)*(uB0+1.f);
    f2 Q1 = (uA1+1.f)*(uB1+1.f);
    f2 Q2 = (uA2+1.f)*(uB2+1.f);
    f2 Q3 = (uA3+1.f)*(uB3+1.f);
    f2 W4, Q4;
    W4.x = __shfl_down(W0.x, 1); W4.y = __shfl_down(W0.y, 1);
    Q4.x = __shfl_down(Q0.x, 1); Q4.y = __shfl_down(Q0.y, 1);

    S.uu2[0]=W0*W1; S.uu2[1]=W1*W2; S.uu2[2]=W2*W3; S.uu2[3]=W3*W4;
    S.vv2[0]=Q0*Q1; S.vv2[1]=Q1*Q2; S.vv2[2]=Q2*Q3; S.vv2[3]=Q3*Q4;

    f2 cs0 = {t0.x+t1.x, t1.x+t2.x};
    f2 cs1 = {t0.y+t1.y, t1.y+t2.y};
    f2 cs2 = {t0.z+t1.z, t1.z+t2.z};
    f2 cs3 = {t0.w+t1.w, t1.w+t2.w};
    f2 cs4; cs4.x = __shfl_down(cs0.x, 1); cs4.y = __shfl_down(cs0.y, 1);
    S.ps[0]=cs0+cs1; S.ps[1]=cs1+cs2; S.ps[2]=cs2+cs3; S.ps[3]=cs3+cs4;
}

__device__ __forceinline__ void do_cubes(const Sl& P, const Sl& C,
        const f2 vAll, const f2 v3,
        f2& aFG, f2& aF255, f2& aBG, f2& aBG0, f2& aSFA,
        f2& c255, f2& c0, f2& cMN)
{
    #pragma unroll
    for (int j = 0; j < 4; ++j) {
        f2 E = P.uu2[j] * C.uu2[j];
        f2 Q = P.vv2[j] * C.vv2[j];
        f2 vj = (j == 3) ? v3 : vAll;
        f2 r; r.x = __builtin_amdgcn_rcpf(Q.x); r.y = __builtin_amdgcn_rcpf(Q.y);
        r *= vj;
        f2 fg = E * r;
        f2 pop = P.ps[j] + C.ps[j];      // exact 0..8
        f2 i255, i0, mn;
        i255.x = fmaxf(pop.x - 7.f, 0.f); i255.y = fmaxf(pop.y - 7.f, 0.f);
        i0.x   = fmaxf(1.f - pop.x, 0.f); i0.y   = fmaxf(1.f - pop.y, 0.f);
        mn.x   = 4.f - fabsf(pop.x - 4.f); mn.y = 4.f - fabsf(pop.y - 4.f);
        mn *= vj;
        aFG  += fg;
        aBG  += r;
        aF255 = fg * i255 + aF255;
        aBG0  = r  * i0   + aBG0;
        c255  = i255 * vj + c255;
        c0    = i0   * vj + c0;
        aSFA  = (fg + r) * mn + aSFA;
        cMN  += mn;
    }
}

// layer body; USEa/USEb = treg set consumed; ISSa/ISSb = treg set refilled
#define LAYER(SRC, DST, Ut0, Ut1, Ut2, Up8, It0, It1, It2, Ip8)                \
    do {                                                                       \
        if (t + 2 <= NT) {                                                     \
            load_tregs(tB, pB, d0 + t + 2, h0, wv, lane, It0, It1, It2, Ip8);  \
            WAITP();                                                           \
        } else {                                                               \
            VMCNT0();                                                          \
        }                                                                      \
        __builtin_amdgcn_s_barrier();                                          \
        if (t + 3 <= NT) stage_slice(pB, d0 + t + 3, smem, sw, h0, wv, lane);  \
        __builtin_amdgcn_sched_barrier(0);                                     \
        make_sl(smem + sr * SLOT_B, wv, lane, Ut0, Ut1, Ut2, Up8, DST);        \
        do_cubes(SRC, DST, vAll, v3, aFG, aF255, aBG, aBG0, aSFA, c255, c0, cMN); \
        if (++sr == NBUF) sr = 0;                                              \
        if (++sw == NBUF) sw = 0;                                              \
    } while (0)

// ws: [1024 blocks][8 partial sums] -- fully overwritten every call, no pre-zero
__global__ __launch_bounds__(256, 4)
void loss_main(const float* __restrict__ preds,
               const float* __restrict__ targets,
               float* __restrict__ ws)
{
    __shared__ __align__(16) char smem[NBUF * SLOT_B];   // 24 KB
    __shared__ float red[32];

    const int lane = threadIdx.x & 63;
    const int wv   = threadIdx.x >> 6;

    // bijective XCD-chunked swizzle: 1024 blocks, 128 contiguous per XCD
    const int nid = ((blockIdx.x & 7) << 7) + (blockIdx.x >> 3);
    const int x = nid & 31;            // h-slab
    const int y = (nid >> 5) & 15;     // d-chunk
    const int b = nid >> 9;            // batch

    const int h0 = x << 3;
    const int d0 = y << 3;
    const int NT = min(CHUNK, OD - d0);   // 8 (last chunk: 7)

    const float* pB = preds   + (size_t)b * DD * SLICE_F;
    const float* tB = targets + (size_t)b * DD * SLICE_F;

    const int   myrow = h0 + (wv << 1);
    const float rv1 = (myrow + 1 < HH - 1) ? 1.f : 0.f;
    const float v63 = (lane == 63) ? 0.f : 1.f;
    const f2 vAll = {1.f, rv1};
    const f2 v3   = {v63, v63 * rv1};

    f2 aFG={0,0}, aF255={0,0}, aBG={0,0}, aBG0={0,0}, aSFA={0,0};
    f2 c255={0,0}, c0={0,0}, cMN={0,0};

    float4 u0={0,0,0,0}, u1=u0, u2=u0, up8=u0;   // treg set 0 (even slices)
    float4 v0=u0, v1=u0, v2=u0, vp8=u0;          // treg set 1 (odd slices)

    // prologue: tregs(0), stage(0), stage(1), tregs(1) -> wait set0+stage0 -> barrier -> stage(2)
    load_tregs(tB, pB, d0,     h0, wv, lane, u0, u1, u2, up8);
    stage_slice(pB, d0,     smem, 0, h0, wv, lane);
    stage_slice(pB, d0 + 1, smem, 1, h0, wv, lane);
    load_tregs(tB, pB, d0 + 1, h0, wv, lane, v0, v1, v2, vp8);
    WAITP();
    __builtin_amdgcn_s_barrier();
    stage_slice(pB, d0 + 2, smem, 2, h0, wv, lane);
    __builtin_amdgcn_sched_barrier(0);

    Sl A, B;
    make_sl(smem, wv, lane, u0, u1, u2, up8, A);   // slice d0 -> A

    int sr = 1, sw = 0;   // read slot of slice t+1; write slot of slice t+3
    int t = 0;
    for (;;) {
        LAYER(A, B, v0, v1, v2, vp8, u0, u1, u2, up8);   // consume set1, refill set0
        if (++t >= NT) break;
        LAYER(B, A, u0, u1, u2, up8, v0, v1, v2, vp8);   // consume set0, refill set1
        if (++t >= NT) break;
    }

    float acc[8] = {aFG.x+aFG.y, aF255.x+aF255.y, c255.x+c255.y,
                    aBG.x+aBG.y, aBG0.x+aBG0.y,   c0.x+c0.y,
                    aSFA.x+aSFA.y, cMN.x+cMN.y};
    #pragma unroll
    for (int i = 0; i < 8; ++i) {
        float v = acc[i];
        #pragma unroll
        for (int off = 32; off > 0; off >>= 1) v += __shfl_xor(v, off);
        acc[i] = v;
    }
    float mine = acc[0];
    mine = (lane == 1) ? acc[1] : mine;
    mine = (lane == 2) ? acc[2] : mine;
    mine = (lane == 3) ? acc[3] : mine;
    mine = (lane == 4) ? acc[4] : mine;
    mine = (lane == 5) ? acc[5] : mine;
    mine = (lane == 6) ? acc[6] : mine;
    mine = (lane == 7) ? acc[7] : mine;
    if (lane < 8) red[wv * 8 + lane] = mine;
    __syncthreads();
    if (wv == 0 && lane < 8)
        ws[nid * 8 + lane] = red[lane] + red[8 + lane] + red[16 + lane] + red[24 + lane];
}

__global__ void loss_final(const float* __restrict__ ws, float* __restrict__ out)
{
    __shared__ float part[16][17];
    __shared__ float S[16];
    const int tid = threadIdx.x;          // 256
    const int c = tid >> 4, sub = tid & 15;
    const int bb = c >> 3, s = c & 7;
    float v = 0.f;
    #pragma unroll 4
    for (int k = 0; k < 32; ++k) {
        int nid = bb * 512 + sub * 32 + k;
        v += ws[nid * 8 + s];
    }
    part[c][sub] = v;
    __syncthreads();
    if (tid < 16) {
        float q = 0.f;
        #pragma unroll
        for (int i = 0; i < 16; ++i) q += part[tid][i];
        S[tid] = q;
    }
    __syncthreads();
    if (tid == 0) {
        const float eps = 1e-5f;
        float dice = 0.f;
        #pragma unroll
        for (int b2 = 0; b2 < 2; ++b2) {
            const float* q = S + b2 * 8;
            float fg_dice = (2.f*q[1] + eps) / (q[0] + q[2] + eps);
            float bg_dice = (2.f*q[4] + eps) / (q[3] + q[5] + eps);
            float q6 = 0.5f * q[6];          // area = 0.5*min(pop,8-pop)
            float q7 = 0.5f * q[7];
            float ss = q7 - q6;              // sum(surf*area)
            float sf_dice = (2.f*ss + eps) / (ss + q7 + eps);
            dice += fg_dice + bg_dice + sf_dice;
        }
        out[0] = 1.f - dice * (1.f/6.f);
    }
}

extern "C" void kernel_launch(void* const* d_in, const int* in_sizes, int n_in,
                              void* d_out, int out_size, void* d_ws, size_t ws_size,
                              hipStream_t stream)
{
    const float* preds   = (const float*)d_in[0];
    const float* targets = (const float*)d_in[1];
    // d_in[2] power / d_in[3] kernel / d_in[4] area are analytic -- baked in
    float* ws = (float*)d_ws;

    loss_main<<<1024, 256, 0, stream>>>(preds, targets, ws);   // 4 blocks/CU exact
    loss_final<<<1, 256, 0, stream>>>(ws, (float*)d_out);
}

// Round 10
// 35.402 us; speedup vs baseline: 4.5770x; 1.3424x over previous
//
#include <hip/hip_runtime.h>

typedef float f2 __attribute__((ext_vector_type(2)));

#define DD 128
#define HH 256
#define WW 256
#define OD 127
#define SLICE_F (HH*WW)
#define CHUNK 8
#define TEN_B 3072          // 3 rows x 1KB per tensor
#define BUF_B 6144          // pred(3KB) + targ(3KB)
#define WAVE_B 12288        // 2 buffers per wave
#define AS1 __attribute__((address_space(1)))
#define AS3 __attribute__((address_space(3)))

#define VMCNT0() asm volatile("s_waitcnt vmcnt(0)" ::: "memory")
#define VMCNT6() asm volatile("s_waitcnt vmcnt(6)" ::: "memory")

struct Sl { f2 uu2[4]; f2 vv2[4]; f2 ps[4]; };

// stage this wave's private 3 pred rows + 3 targ rows of one slice (6 x gload_lds)
__device__ __forceinline__ void stage_slice(const float* __restrict__ pB,
                                            const float* __restrict__ tB,
                                            int s, char* lb, int h0w, int lane)
{
    const size_t so = ((size_t)s << 16) + (size_t)(lane << 2);
    #pragma unroll
    for (int r = 0; r < 3; ++r) {
        const int grow = min(h0w + r, HH - 1);
        const float* gp = pB + so + ((size_t)grow << 8);
        const float* gt = tB + so + ((size_t)grow << 8);
        __builtin_amdgcn_global_load_lds((const AS1 void*)gp,
            (AS3 void*)(lb + r * 1024 + lane * 16), 16, 0, 0);
        __builtin_amdgcn_global_load_lds((const AS1 void*)gt,
            (AS3 void*)(lb + TEN_B + r * 1024 + lane * 16), 16, 0, 0);
    }
}

__device__ __forceinline__ void make_sl(const char* lb, int lane, Sl& S)
{
    const float* sp = (const float*)lb;
    const float* st = (const float*)(lb + TEN_B);
    const int co = lane << 2;
    const float4 p0 = *(const float4*)(sp + co);
    const float4 p1 = *(const float4*)(sp + co + 256);
    const float4 p2 = *(const float4*)(sp + co + 512);
    const float4 t0 = *(const float4*)(st + co);
    const float4 t1 = *(const float4*)(st + co + 256);
    const float4 t2 = *(const float4*)(st + co + 512);

    float u0x=__expf(p0.x), u0y=__expf(p0.y), u0z=__expf(p0.z), u0w=__expf(p0.w);
    float u1x=__expf(p1.x), u1y=__expf(p1.y), u1z=__expf(p1.z), u1w=__expf(p1.w);
    float u2x=__expf(p2.x), u2y=__expf(p2.y), u2z=__expf(p2.z), u2w=__expf(p2.w);

    f2 uA0 = {u0x,u1x}, uB0 = {u1x,u2x};
    f2 uA1 = {u0y,u1y}, uB1 = {u1y,u2y};
    f2 uA2 = {u0z,u1z}, uB2 = {u1z,u2z};
    f2 uA3 = {u0w,u1w}, uB3 = {u1w,u2w};

    f2 W0 = uA0*uB0, W1 = uA1*uB1, W2 = uA2*uB2, W3 = uA3*uB3;
    f2 Q0 = (uA0+1.f)*(uB0+1.f);
    f2 Q1 = (uA1+1.f)*(uB1+1.f);
    f2 Q2 = (uA2+1.f)*(uB2+1.f);
    f2 Q3 = (uA3+1.f)*(uB3+1.f);
    f2 W4, Q4;
    W4.x = __shfl_down(W0.x, 1); W4.y = __shfl_down(W0.y, 1);
    Q4.x = __shfl_down(Q0.x, 1); Q4.y = __shfl_down(Q0.y, 1);

    S.uu2[0]=W0*W1; S.uu2[1]=W1*W2; S.uu2[2]=W2*W3; S.uu2[3]=W3*W4;
    S.vv2[0]=Q0*Q1; S.vv2[1]=Q1*Q2; S.vv2[2]=Q2*Q3; S.vv2[3]=Q3*Q4;

    f2 cs0 = {t0.x+t1.x, t1.x+t2.x};
    f2 cs1 = {t0.y+t1.y, t1.y+t2.y};
    f2 cs2 = {t0.z+t1.z, t1.z+t2.z};
    f2 cs3 = {t0.w+t1.w, t1.w+t2.w};
    f2 cs4; cs4.x = __shfl_down(cs0.x, 1); cs4.y = __shfl_down(cs0.y, 1);
    S.ps[0]=cs0+cs1; S.ps[1]=cs1+cs2; S.ps[2]=cs2+cs3; S.ps[3]=cs3+cs4;
}

__device__ __forceinline__ void do_cubes(const Sl& P, const Sl& C,
        const f2 vAll, const f2 v3,
        f2& aFG, f2& aF255, f2& aBG, f2& aBG0, f2& aSFA,
        f2& c255, f2& c0, f2& cMN)
{
    #pragma unroll
    for (int j = 0; j < 4; ++j) {
        f2 E = P.uu2[j] * C.uu2[j];
        f2 Q = P.vv2[j] * C.vv2[j];
        f2 vj = (j == 3) ? v3 : vAll;
        f2 r; r.x = __builtin_amdgcn_rcpf(Q.x); r.y = __builtin_amdgcn_rcpf(Q.y);
        r *= vj;
        f2 fg = E * r;
        f2 pop = P.ps[j] + C.ps[j];      // exact 0..8
        f2 i255, i0, mn;
        i255.x = fmaxf(pop.x - 7.f, 0.f); i255.y = fmaxf(pop.y - 7.f, 0.f);
        i0.x   = fmaxf(1.f - pop.x, 0.f); i0.y   = fmaxf(1.f - pop.y, 0.f);
        mn.x   = 4.f - fabsf(pop.x - 4.f); mn.y = 4.f - fabsf(pop.y - 4.f);
        mn *= vj;
        aFG  += fg;
        aBG  += r;
        aF255 = fg * i255 + aF255;
        aBG0  = r  * i0   + aBG0;
        c255  = i255 * vj + c255;
        c0    = i0   * vj + c0;
        aSFA  = (fg + r) * mn + aSFA;
        cMN  += mn;
    }
}

// per-wave pipeline step, NO barriers anywhere in the loop
#define LAYER(SRC, DST)                                                        \
    do {                                                                       \
        if (t + 2 <= NT) {                                                     \
            stage_slice(pB, tB, d0 + t + 2, wb + (t & 1) * BUF_B, h0w, lane);  \
            VMCNT6();          /* 6 outstanding = the stage just issued */     \
        } else {                                                               \
            VMCNT0();                                                          \
        }                                                                      \
        __builtin_amdgcn_sched_barrier(0);                                     \
        make_sl(wb + ((t + 1) & 1) * BUF_B, lane, DST);                        \
        do_cubes(SRC, DST, vAll, v3, aFG, aF255, aBG, aBG0, aSFA, c255, c0, cMN); \
    } while (0)

// ws: [1024 blocks][8 partial sums] -- fully overwritten every call, no pre-zero
__global__ __launch_bounds__(256, 3)
void loss_main(const float* __restrict__ preds,
               const float* __restrict__ targets,
               float* __restrict__ ws)
{
    __shared__ __align__(16) char smem[4 * WAVE_B];   // 48 KB, per-wave private
    __shared__ float red[32];

    const int lane = threadIdx.x & 63;
    const int wv   = threadIdx.x >> 6;
    char* wb = smem + wv * WAVE_B;

    // bijective XCD-chunked swizzle: 1024 blocks, 128 contiguous per XCD
    const int nid = ((blockIdx.x & 7) << 7) + (blockIdx.x >> 3);
    const int x = nid & 31;            // h-slab
    const int y = (nid >> 5) & 15;     // d-chunk
    const int b = nid >> 9;            // batch

    const int h0w = (x << 3) + (wv << 1);   // this wave's first cube row
    const int d0  = y << 3;
    const int NT  = min(CHUNK, OD - d0);    // 8 (last chunk: 7)

    const float* pB = preds   + (size_t)b * DD * SLICE_F;
    const float* tB = targets + (size_t)b * DD * SLICE_F;

    const float rv1 = (h0w + 1 < HH - 1) ? 1.f : 0.f;
    const float v63 = (lane == 63) ? 0.f : 1.f;
    const f2 vAll = {1.f, rv1};
    const f2 v3   = {v63, v63 * rv1};

    f2 aFG={0,0}, aF255={0,0}, aBG={0,0}, aBG0={0,0}, aSFA={0,0};
    f2 c255={0,0}, c0={0,0}, cMN={0,0};

    // prologue: stage slices 0,1 into this wave's two buffers
    stage_slice(pB, tB, d0,     wb,         h0w, lane);
    stage_slice(pB, tB, d0 + 1, wb + BUF_B, h0w, lane);
    VMCNT6();                              // slice 0 landed (slice 1 in flight)
    __builtin_amdgcn_sched_barrier(0);

    Sl A, B;
    make_sl(wb, lane, A);                  // slice d0 -> A

    int t = 0;
    for (;;) {
        LAYER(A, B);
        if (++t >= NT) break;
        LAYER(B, A);
        if (++t >= NT) break;
    }

    float acc[8] = {aFG.x+aFG.y, aF255.x+aF255.y, c255.x+c255.y,
                    aBG.x+aBG.y, aBG0.x+aBG0.y,   c0.x+c0.y,
                    aSFA.x+aSFA.y, cMN.x+cMN.y};
    #pragma unroll
    for (int i = 0; i < 8; ++i) {
        float v = acc[i];
        #pragma unroll
        for (int off = 32; off > 0; off >>= 1) v += __shfl_xor(v, off);
        acc[i] = v;
    }
    float mine = acc[0];
    mine = (lane == 1) ? acc[1] : mine;
    mine = (lane == 2) ? acc[2] : mine;
    mine = (lane == 3) ? acc[3] : mine;
    mine = (lane == 4) ? acc[4] : mine;
    mine = (lane == 5) ? acc[5] : mine;
    mine = (lane == 6) ? acc[6] : mine;
    mine = (lane == 7) ? acc[7] : mine;
    if (lane < 8) red[wv * 8 + lane] = mine;
    __syncthreads();
    if (wv == 0 && lane < 8)
        ws[nid * 8 + lane] = red[lane] + red[8 + lane] + red[16 + lane] + red[24 + lane];
}

__global__ void loss_final(const float* __restrict__ ws, float* __restrict__ out)
{
    __shared__ float part[16][17];
    __shared__ float S[16];
    const int tid = threadIdx.x;          // 256
    const int c = tid >> 4, sub = tid & 15;
    const int bb = c >> 3, s = c & 7;
    float v = 0.f;
    #pragma unroll 4
    for (int k = 0; k < 32; ++k) {
        int nid = bb * 512 + sub * 32 + k;
        v += ws[nid * 8 + s];
    }
    part[c][sub] = v;
    __syncthreads();
    if (tid < 16) {
        float q = 0.f;
        #pragma unroll
        for (int i = 0; i < 16; ++i) q += part[tid][i];
        S[tid] = q;
    }
    __syncthreads();
    if (tid == 0) {
        const float eps = 1e-5f;
        float dice = 0.f;
        #pragma unroll
        for (int b2 = 0; b2 < 2; ++b2) {
            const float* q = S + b2 * 8;
            float fg_dice = (2.f*q[1] + eps) / (q[0] + q[2] + eps);
            float bg_dice = (2.f*q[4] + eps) / (q[3] + q[5] + eps);
            float q6 = 0.5f * q[6];          // area = 0.5*min(pop,8-pop)
            float q7 = 0.5f * q[7];
            float ss = q7 - q6;              // sum(surf*area)
            float sf_dice = (2.f*ss + eps) / (ss + q7 + eps);
            dice += fg_dice + bg_dice + sf_dice;
        }
        out[0] = 1.f - dice * (1.f/6.f);
    }
}

extern "C" void kernel_launch(void* const* d_in, const int* in_sizes, int n_in,
                              void* d_out, int out_size, void* d_ws, size_t ws_size,
                              hipStream_t stream)
{
    const float* preds   = (const float*)d_in[0];
    const float* targets = (const float*)d_in[1];
    // d_in[2] power / d_in[3] kernel / d_in[4] area are analytic -- baked in
    float* ws = (float*)d_ws;

    loss_main<<<1024, 256, 0, stream>>>(preds, targets, ws);   // 3 blocks/CU (LDS-capped)
    loss_final<<<1, 256, 0, stream>>>(ws, (float*)d_out);
}

// Round 11
// 34.752 us; speedup vs baseline: 4.6626x; 1.0187x over previous
//
#include <hip/hip_runtime.h>

typedef float f2 __attribute__((ext_vector_type(2)));

#define DD 128
#define HH 256
#define WW 256
#define OD 127
#define SLICE_F (HH*WW)
#define CHUNK 16
#define TEN_B 3072          // 3 rows x 1KB per tensor
#define BUF_B 6144          // pred(3KB) + targ(3KB)
#define NBUF 3
#define WAVE_B (NBUF*BUF_B) // 18 KB per wave
#define AS1 __attribute__((address_space(1)))
#define AS3 __attribute__((address_space(3)))

#define VMCNT0()  asm volatile("s_waitcnt vmcnt(0)"  ::: "memory")
#define VMCNT6()  asm volatile("s_waitcnt vmcnt(6)"  ::: "memory")
#define VMCNT12() asm volatile("s_waitcnt vmcnt(12)" ::: "memory")

struct Sl { f2 uu2[4]; f2 vv2[4]; f2 ps[4]; };

// stage this wave's private 3 pred rows + 3 targ rows of one slice (6 x gload_lds)
__device__ __forceinline__ void stage_slice(const float* __restrict__ pB,
                                            const float* __restrict__ tB,
                                            int s, char* lb, int h0w, int lane)
{
    const size_t so = ((size_t)s << 16) + (size_t)(lane << 2);
    #pragma unroll
    for (int r = 0; r < 3; ++r) {
        const int grow = min(h0w + r, HH - 1);
        const float* gp = pB + so + ((size_t)grow << 8);
        const float* gt = tB + so + ((size_t)grow << 8);
        __builtin_amdgcn_global_load_lds((const AS1 void*)gp,
            (AS3 void*)(lb + r * 1024 + lane * 16), 16, 0, 0);
        __builtin_amdgcn_global_load_lds((const AS1 void*)gt,
            (AS3 void*)(lb + TEN_B + r * 1024 + lane * 16), 16, 0, 0);
    }
}

__device__ __forceinline__ void make_sl(const char* lb, int lane, Sl& S)
{
    const float* sp = (const float*)lb;
    const float* st = (const float*)(lb + TEN_B);
    const int co = lane << 2;
    const float4 p0 = *(const float4*)(sp + co);
    const float4 p1 = *(const float4*)(sp + co + 256);
    const float4 p2 = *(const float4*)(sp + co + 512);
    const float4 t0 = *(const float4*)(st + co);
    const float4 t1 = *(const float4*)(st + co + 256);
    const float4 t2 = *(const float4*)(st + co + 512);

    float u0x=__expf(p0.x), u0y=__expf(p0.y), u0z=__expf(p0.z), u0w=__expf(p0.w);
    float u1x=__expf(p1.x), u1y=__expf(p1.y), u1z=__expf(p1.z), u1w=__expf(p1.w);
    float u2x=__expf(p2.x), u2y=__expf(p2.y), u2z=__expf(p2.z), u2w=__expf(p2.w);

    f2 uA0 = {u0x,u1x}, uB0 = {u1x,u2x};
    f2 uA1 = {u0y,u1y}, uB1 = {u1y,u2y};
    f2 uA2 = {u0z,u1z}, uB2 = {u1z,u2z};
    f2 uA3 = {u0w,u1w}, uB3 = {u1w,u2w};

    f2 W0 = uA0*uB0, W1 = uA1*uB1, W2 = uA2*uB2, W3 = uA3*uB3;
    f2 Q0 = (uA0+1.f)*(uB0+1.f);
    f2 Q1 = (uA1+1.f)*(uB1+1.f);
    f2 Q2 = (uA2+1.f)*(uB2+1.f);
    f2 Q3 = (uA3+1.f)*(uB3+1.f);
    f2 W4, Q4;
    W4.x = __shfl_down(W0.x, 1); W4.y = __shfl_down(W0.y, 1);
    Q4.x = __shfl_down(Q0.x, 1); Q4.y = __shfl_down(Q0.y, 1);

    S.uu2[0]=W0*W1; S.uu2[1]=W1*W2; S.uu2[2]=W2*W3; S.uu2[3]=W3*W4;
    S.vv2[0]=Q0*Q1; S.vv2[1]=Q1*Q2; S.vv2[2]=Q2*Q3; S.vv2[3]=Q3*Q4;

    f2 cs0 = {t0.x+t1.x, t1.x+t2.x};
    f2 cs1 = {t0.y+t1.y, t1.y+t2.y};
    f2 cs2 = {t0.z+t1.z, t1.z+t2.z};
    f2 cs3 = {t0.w+t1.w, t1.w+t2.w};
    f2 cs4; cs4.x = __shfl_down(cs0.x, 1); cs4.y = __shfl_down(cs0.y, 1);
    S.ps[0]=cs0+cs1; S.ps[1]=cs1+cs2; S.ps[2]=cs2+cs3; S.ps[3]=cs3+cs4;
}

__device__ __forceinline__ void do_cubes(const Sl& P, const Sl& C,
        const f2 vAll, const f2 v3,
        f2& aFG, f2& aF255, f2& aBG, f2& aBG0, f2& aSFA,
        f2& c255, f2& c0, f2& cMN)
{
    #pragma unroll
    for (int j = 0; j < 4; ++j) {
        f2 E = P.uu2[j] * C.uu2[j];
        f2 Q = P.vv2[j] * C.vv2[j];
        f2 vj = (j == 3) ? v3 : vAll;
        f2 r; r.x = __builtin_amdgcn_rcpf(Q.x); r.y = __builtin_amdgcn_rcpf(Q.y);
        r *= vj;
        f2 fg = E * r;
        f2 pop = P.ps[j] + C.ps[j];      // exact 0..8
        f2 i255, i0, mn;
        i255.x = fmaxf(pop.x - 7.f, 0.f); i255.y = fmaxf(pop.y - 7.f, 0.f);
        i0.x   = fmaxf(1.f - pop.x, 0.f); i0.y   = fmaxf(1.f - pop.y, 0.f);
        mn.x   = 4.f - fabsf(pop.x - 4.f); mn.y = 4.f - fabsf(pop.y - 4.f);
        mn *= vj;
        aFG  += fg;
        aBG  += r;
        aF255 = fg * i255 + aF255;
        aBG0  = r  * i0   + aBG0;
        c255  = i255 * vj + c255;
        c0    = i0   * vj + c0;
        aSFA  = (fg + r) * mn + aSFA;
        cMN  += mn;
    }
}

// per-wave depth-2 pipeline step, NO barriers
#define LAYER(SRC, DST)                                                        \
    do {                                                                       \
        if (t + 3 <= NT) {                                                     \
            stage_slice(pB, tB, d0 + t + 3, wb + sw * BUF_B, h0w, lane);       \
            VMCNT12();   /* slices t+2,t+3 in flight; t+1 landed */            \
        } else if (t + 2 <= NT) {                                              \
            VMCNT6();    /* only slice t+2 in flight */                        \
        } else {                                                               \
            VMCNT0();                                                          \
        }                                                                      \
        __builtin_amdgcn_sched_barrier(0);                                     \
        make_sl(wb + sr * BUF_B, lane, DST);                                   \
        do_cubes(SRC, DST, vAll, v3, aFG, aF255, aBG, aBG0, aSFA, c255, c0, cMN); \
        sr = (sr + 1 == NBUF) ? 0 : sr + 1;                                    \
        sw = (sw + 1 == NBUF) ? 0 : sw + 1;                                    \
    } while (0)

// ws: [512 blocks][8 partial sums] -- fully overwritten every call, no pre-zero
__global__ __launch_bounds__(256, 2)
void loss_main(const float* __restrict__ preds,
               const float* __restrict__ targets,
               float* __restrict__ ws)
{
    __shared__ __align__(16) char smem[4 * WAVE_B];   // 72 KB, per-wave private
    __shared__ float red[32];

    const int lane = threadIdx.x & 63;
    const int wv   = threadIdx.x >> 6;
    char* wb = smem + wv * WAVE_B;

    // bijective XCD-chunked swizzle: 512 blocks, 64 contiguous per XCD
    const int nid = ((blockIdx.x & 7) << 6) + (blockIdx.x >> 3);
    const int x = nid & 31;            // h-slab
    const int y = (nid >> 5) & 7;      // d-chunk
    const int b = nid >> 8;            // batch

    const int h0w = (x << 3) + (wv << 1);   // this wave's first cube row
    const int d0  = y << 4;
    const int NT  = min(CHUNK, OD - d0);    // 16 (last chunk: 15)

    const float* pB = preds   + (size_t)b * DD * SLICE_F;
    const float* tB = targets + (size_t)b * DD * SLICE_F;

    const float rv1 = (h0w + 1 < HH - 1) ? 1.f : 0.f;
    const float v63 = (lane == 63) ? 0.f : 1.f;
    const f2 vAll = {1.f, rv1};
    const f2 v3   = {v63, v63 * rv1};

    f2 aFG={0,0}, aF255={0,0}, aBG={0,0}, aBG0={0,0}, aSFA={0,0};
    f2 c255={0,0}, c0={0,0}, cMN={0,0};

    // prologue: stage slices 0,1,2 into this wave's three slots
    stage_slice(pB, tB, d0,     wb,             h0w, lane);
    stage_slice(pB, tB, d0 + 1, wb + BUF_B,     h0w, lane);
    stage_slice(pB, tB, d0 + 2, wb + 2 * BUF_B, h0w, lane);
    VMCNT12();                             // slice 0 landed (1,2 in flight)
    __builtin_amdgcn_sched_barrier(0);

    Sl A, B;
    make_sl(wb, lane, A);                  // slice d0 -> A

    int sr = 1, sw = 0;   // read slot of slice t+1; write slot of slice t+3
    int t = 0;
    for (;;) {
        LAYER(A, B);
        if (++t >= NT) break;
        LAYER(B, A);
        if (++t >= NT) break;
    }

    float acc[8] = {aFG.x+aFG.y, aF255.x+aF255.y, c255.x+c255.y,
                    aBG.x+aBG.y, aBG0.x+aBG0.y,   c0.x+c0.y,
                    aSFA.x+aSFA.y, cMN.x+cMN.y};
    #pragma unroll
    for (int i = 0; i < 8; ++i) {
        float v = acc[i];
        #pragma unroll
        for (int off = 32; off > 0; off >>= 1) v += __shfl_xor(v, off);
        acc[i] = v;
    }
    float mine = acc[0];
    mine = (lane == 1) ? acc[1] : mine;
    mine = (lane == 2) ? acc[2] : mine;
    mine = (lane == 3) ? acc[3] : mine;
    mine = (lane == 4) ? acc[4] : mine;
    mine = (lane == 5) ? acc[5] : mine;
    mine = (lane == 6) ? acc[6] : mine;
    mine = (lane == 7) ? acc[7] : mine;
    if (lane < 8) red[wv * 8 + lane] = mine;
    __syncthreads();
    if (wv == 0 && lane < 8)
        ws[nid * 8 + lane] = red[lane] + red[8 + lane] + red[16 + lane] + red[24 + lane];
}

__global__ void loss_final(const float* __restrict__ ws, float* __restrict__ out)
{
    __shared__ float part[16][17];
    __shared__ float S[16];
    const int tid = threadIdx.x;          // 256
    const int c = tid >> 4, sub = tid & 15;
    const int bb = c >> 3, s = c & 7;
    float v = 0.f;
    #pragma unroll 4
    for (int k = 0; k < 16; ++k) {
        int nid = bb * 256 + sub * 16 + k;
        v += ws[nid * 8 + s];
    }
    part[c][sub] = v;
    __syncthreads();
    if (tid < 16) {
        float q = 0.f;
        #pragma unroll
        for (int i = 0; i < 16; ++i) q += part[tid][i];
        S[tid] = q;
    }
    __syncthreads();
    if (tid == 0) {
        const float eps = 1e-5f;
        float dice = 0.f;
        #pragma unroll
        for (int b2 = 0; b2 < 2; ++b2) {
            const float* q = S + b2 * 8;
            float fg_dice = (2.f*q[1] + eps) / (q[0] + q[2] + eps);
            float bg_dice = (2.f*q[4] + eps) / (q[3] + q[5] + eps);
            float q6 = 0.5f * q[6];          // area = 0.5*min(pop,8-pop)
            float q7 = 0.5f * q[7];
            float ss = q7 - q6;              // sum(surf*area)
            float sf_dice = (2.f*ss + eps) / (ss + q7 + eps);
            dice += fg_dice + bg_dice + sf_dice;
        }
        out[0] = 1.f - dice * (1.f/6.f);
    }
}

extern "C" void kernel_launch(void* const* d_in, const int* in_sizes, int n_in,
                              void* d_out, int out_size, void* d_ws, size_t ws_size,
                              hipStream_t stream)
{
    const float* preds   = (const float*)d_in[0];
    const float* targets = (const float*)d_in[1];
    // d_in[2] power / d_in[3] kernel / d_in[4] area are analytic -- baked in
    float* ws = (float*)d_ws;

    loss_main<<<512, 256, 0, stream>>>(preds, targets, ws);   // 2 blocks/CU exact
    loss_final<<<1, 256, 0, stream>>>(ws, (float*)d_out);
}

// Round 12
// 32.605 us; speedup vs baseline: 4.9697x; 1.0659x over previous
//
#include <hip/hip_runtime.h>

typedef float f2 __attribute__((ext_vector_type(2)));

#define DD 128
#define HH 256
#define WW 256
#define OD 127
#define SLICE_F (HH*WW)
#define CHUNK 16
#define TEN_B 9216          // 9 rows x 1KB per tensor
#define SLOT_B 18432        // pred 9 rows + targ 9 rows
#define NBUF 4
#define AS1 __attribute__((address_space(1)))
#define AS3 __attribute__((address_space(3)))

// per-wave counted waits (waves 0,1 issue 5 loads/slice; waves 2,3 issue 4)
#define WAITP() do { if (wv < 2) asm volatile("s_waitcnt vmcnt(10)" ::: "memory"); \
                     else        asm volatile("s_waitcnt vmcnt(8)"  ::: "memory"); } while (0)
#define WAIT1() do { if (wv < 2) asm volatile("s_waitcnt vmcnt(5)"  ::: "memory"); \
                     else        asm volatile("s_waitcnt vmcnt(4)"  ::: "memory"); } while (0)
#define WAIT0() asm volatile("s_waitcnt vmcnt(0)" ::: "memory")

struct Sl { f2 uu2[4]; f2 vv2[4]; f2 ps[4]; };

// stage one slice: 9 pred rows + 9 targ rows -> one LDS slot (18 loads, split 5/5/4/4)
__device__ __forceinline__ void stage_slice(const float* __restrict__ pB,
                                            const float* __restrict__ tB,
                                            int s, char* lb, int h0, int wv, int lane)
{
    #pragma unroll
    for (int i = 0; i < 5; ++i) {
        const int L = i * 4 + wv;                 // 0..19, wave-uniform predicate
        if (L < 18) {
            const int T = (L >= 9) ? 1 : 0;       // 0=pred 1=targ
            const int r = L - T * 9;              // row slot 0..8
            const int grow = min(h0 + r, HH - 1);
            const float* g = (T ? tB : pB)
                           + ((size_t)s << 16) + ((size_t)grow << 8) + (lane << 2);
            void* l = lb + T * TEN_B + r * 1024 + lane * 16;
            __builtin_amdgcn_global_load_lds((const AS1 void*)g, (AS3 void*)l, 16, 0, 0);
        }
    }
}

__device__ __forceinline__ void make_sl(const char* lb, int wv, int lane, Sl& S)
{
    const float* sp = (const float*)lb;
    const float* st = (const float*)(lb + TEN_B);
    const int ro = ((wv << 1) << 8) + (lane << 2);   // row 2*wv, col lane*4
    const float4 p0 = *(const float4*)(sp + ro);
    const float4 p1 = *(const float4*)(sp + ro + 256);
    const float4 p2 = *(const float4*)(sp + ro + 512);
    const float4 t0 = *(const float4*)(st + ro);
    const float4 t1 = *(const float4*)(st + ro + 256);
    const float4 t2 = *(const float4*)(st + ro + 512);

    float u0x=__expf(p0.x), u0y=__expf(p0.y), u0z=__expf(p0.z), u0w=__expf(p0.w);
    float u1x=__expf(p1.x), u1y=__expf(p1.y), u1z=__expf(p1.z), u1w=__expf(p1.w);
    float u2x=__expf(p2.x), u2y=__expf(p2.y), u2z=__expf(p2.z), u2w=__expf(p2.w);

    f2 uA0 = {u0x,u1x}, uB0 = {u1x,u2x};
    f2 uA1 = {u0y,u1y}, uB1 = {u1y,u2y};
    f2 uA2 = {u0z,u1z}, uB2 = {u1z,u2z};
    f2 uA3 = {u0w,u1w}, uB3 = {u1w,u2w};

    f2 W0 = uA0*uB0, W1 = uA1*uB1, W2 = uA2*uB2, W3 = uA3*uB3;
    f2 Q0 = (uA0+1.f)*(uB0+1.f);
    f2 Q1 = (uA1+1.f)*(uB1+1.f);
    f2 Q2 = (uA2+1.f)*(uB2+1.f);
    f2 Q3 = (uA3+1.f)*(uB3+1.f);
    f2 W4, Q4;
    W4.x = __shfl_down(W0.x, 1); W4.y = __shfl_down(W0.y, 1);
    Q4.x = __shfl_down(Q0.x, 1); Q4.y = __shfl_down(Q0.y, 1);

    S.uu2[0]=W0*W1; S.uu2[1]=W1*W2; S.uu2[2]=W2*W3; S.uu2[3]=W3*W4;
    S.vv2[0]=Q0*Q1; S.vv2[1]=Q1*Q2; S.vv2[2]=Q2*Q3; S.vv2[3]=Q3*Q4;

    f2 cs0 = {t0.x+t1.x, t1.x+t2.x};
    f2 cs1 = {t0.y+t1.y, t1.y+t2.y};
    f2 cs2 = {t0.z+t1.z, t1.z+t2.z};
    f2 cs3 = {t0.w+t1.w, t1.w+t2.w};
    f2 cs4; cs4.x = __shfl_down(cs0.x, 1); cs4.y = __shfl_down(cs0.y, 1);
    S.ps[0]=cs0+cs1; S.ps[1]=cs1+cs2; S.ps[2]=cs2+cs3; S.ps[3]=cs3+cs4;
}

__device__ __forceinline__ void do_cubes(const Sl& P, const Sl& C,
        const f2 vAll, const f2 v3,
        f2& aFG, f2& aF255, f2& aBG, f2& aBG0, f2& aSFA,
        f2& c255, f2& c0, f2& cMN)
{
    #pragma unroll
    for (int j = 0; j < 4; ++j) {
        f2 E = P.uu2[j] * C.uu2[j];
        f2 Q = P.vv2[j] * C.vv2[j];
        f2 vj = (j == 3) ? v3 : vAll;
        f2 r; r.x = __builtin_amdgcn_rcpf(Q.x); r.y = __builtin_amdgcn_rcpf(Q.y);
        r *= vj;
        f2 fg = E * r;
        f2 pop = P.ps[j] + C.ps[j];      // exact 0..8
        f2 i255, i0, mn;
        i255.x = fmaxf(pop.x - 7.f, 0.f); i255.y = fmaxf(pop.y - 7.f, 0.f);
        i0.x   = fmaxf(1.f - pop.x, 0.f); i0.y   = fmaxf(1.f - pop.y, 0.f);
        mn.x   = 4.f - fabsf(pop.x - 4.f); mn.y = 4.f - fabsf(pop.y - 4.f);
        mn *= vj;
        aFG  += fg;
        aBG  += r;
        aF255 = fg * i255 + aF255;
        aBG0  = r  * i0   + aBG0;
        c255  = i255 * vj + c255;
        c0    = i0   * vj + c0;
        aSFA  = (fg + r) * mn + aSFA;
        cMN  += mn;
    }
}

// shared depth-2 pipeline step: stage before barrier, counted waits (never drain mid-loop)
#define LAYER(SRC, DST)                                                        \
    do {                                                                       \
        if (t + 3 <= NT) {                                                     \
            stage_slice(pB, tB, d0 + t + 3, smem + sw * SLOT_B, h0, wv, lane); \
            WAITP();   /* own loads of t+2,t+3 outstanding; t+1 landed */      \
        } else if (t + 2 <= NT) {                                              \
            WAIT1();   /* only t+2 outstanding */                              \
        } else {                                                               \
            WAIT0();                                                           \
        }                                                                      \
        __builtin_amdgcn_s_barrier();                                          \
        __builtin_amdgcn_sched_barrier(0);                                     \
        make_sl(smem + sr * SLOT_B, wv, lane, DST);                            \
        do_cubes(SRC, DST, vAll, v3, aFG, aF255, aBG, aBG0, aSFA, c255, c0, cMN); \
        sr = (sr + 1) & 3;                                                     \
        sw = (sw + 1) & 3;                                                     \
    } while (0)

// ws: [512 blocks][8 partial sums] -- fully overwritten every call, no pre-zero
__global__ __launch_bounds__(256, 2)
void loss_main(const float* __restrict__ preds,
               const float* __restrict__ targets,
               float* __restrict__ ws)
{
    __shared__ __align__(16) char smem[NBUF * SLOT_B];   // 72 KB shared slots
    __shared__ float red[32];

    const int lane = threadIdx.x & 63;
    const int wv   = threadIdx.x >> 6;

    // bijective XCD-chunked swizzle: 512 blocks, 64 contiguous per XCD
    const int nid = ((blockIdx.x & 7) << 6) + (blockIdx.x >> 3);
    const int x = nid & 31;            // h-slab
    const int y = (nid >> 5) & 7;      // d-chunk
    const int b = nid >> 8;            // batch

    const int h0 = x << 3;                  // block's first cube row (8 rows)
    const int d0 = y << 4;
    const int NT = min(CHUNK, OD - d0);     // 16 (last chunk: 15)

    const float* pB = preds   + (size_t)b * DD * SLICE_F;
    const float* tB = targets + (size_t)b * DD * SLICE_F;

    const int   myrow = h0 + (wv << 1);
    const float rv1 = (myrow + 1 < HH - 1) ? 1.f : 0.f;
    const float v63 = (lane == 63) ? 0.f : 1.f;
    const f2 vAll = {1.f, rv1};
    const f2 v3   = {v63, v63 * rv1};

    f2 aFG={0,0}, aF255={0,0}, aBG={0,0}, aBG0={0,0}, aSFA={0,0};
    f2 c255={0,0}, c0={0,0}, cMN={0,0};

    // prologue: stage slices 0,1,2 into slots 0,1,2
    stage_slice(pB, tB, d0,     smem,             h0, wv, lane);
    stage_slice(pB, tB, d0 + 1, smem + SLOT_B,    h0, wv, lane);
    stage_slice(pB, tB, d0 + 2, smem + 2*SLOT_B,  h0, wv, lane);
    WAITP();                               // slice 0 landed (1,2 in flight)
    __builtin_amdgcn_s_barrier();
    __builtin_amdgcn_sched_barrier(0);

    Sl A, B;
    make_sl(smem, wv, lane, A);            // slice d0 -> A

    int sr = 1, sw = 3;   // read slot of slice t+1; write slot of slice t+3
    int t = 0;
    for (;;) {
        LAYER(A, B);
        if (++t >= NT) break;
        LAYER(B, A);
        if (++t >= NT) break;
    }

    float acc[8] = {aFG.x+aFG.y, aF255.x+aF255.y, c255.x+c255.y,
                    aBG.x+aBG.y, aBG0.x+aBG0.y,   c0.x+c0.y,
                    aSFA.x+aSFA.y, cMN.x+cMN.y};
    #pragma unroll
    for (int i = 0; i < 8; ++i) {
        float v = acc[i];
        #pragma unroll
        for (int off = 32; off > 0; off >>= 1) v += __shfl_xor(v, off);
        acc[i] = v;
    }
    float mine = acc[0];
    mine = (lane == 1) ? acc[1] : mine;
    mine = (lane == 2) ? acc[2] : mine;
    mine = (lane == 3) ? acc[3] : mine;
    mine = (lane == 4) ? acc[4] : mine;
    mine = (lane == 5) ? acc[5] : mine;
    mine = (lane == 6) ? acc[6] : mine;
    mine = (lane == 7) ? acc[7] : mine;
    if (lane < 8) red[wv * 8 + lane] = mine;
    __syncthreads();
    if (wv == 0 && lane < 8)
        ws[nid * 8 + lane] = red[lane] + red[8 + lane] + red[16 + lane] + red[24 + lane];
}

__global__ void loss_final(const float* __restrict__ ws, float* __restrict__ out)
{
    __shared__ float part[16][17];
    __shared__ float S[16];
    const int tid = threadIdx.x;          // 256
    const int c = tid >> 4, sub = tid & 15;
    const int bb = c >> 3, s = c & 7;
    float v = 0.f;
    #pragma unroll 4
    for (int k = 0; k < 16; ++k) {
        int nid = bb * 256 + sub * 16 + k;
        v += ws[nid * 8 + s];
    }
    part[c][sub] = v;
    __syncthreads();
    if (tid < 16) {
        float q = 0.f;
        #pragma unroll
        for (int i = 0; i < 16; ++i) q += part[tid][i];
        S[tid] = q;
    }
    __syncthreads();
    if (tid == 0) {
        const float eps = 1e-5f;
        float dice = 0.f;
        #pragma unroll
        for (int b2 = 0; b2 < 2; ++b2) {
            const float* q = S + b2 * 8;
            float fg_dice = (2.f*q[1] + eps) / (q[0] + q[2] + eps);
            float bg_dice = (2.f*q[4] + eps) / (q[3] + q[5] + eps);
            float q6 = 0.5f * q[6];          // area = 0.5*min(pop,8-pop)
            float q7 = 0.5f * q[7];
            float ss = q7 - q6;              // sum(surf*area)
            float sf_dice = (2.f*ss + eps) / (ss + q7 + eps);
            dice += fg_dice + bg_dice + sf_dice;
        }
        out[0] = 1.f - dice * (1.f/6.f);
    }
}

extern "C" void kernel_launch(void* const* d_in, const int* in_sizes, int n_in,
                              void* d_out, int out_size, void* d_ws, size_t ws_size,
                              hipStream_t stream)
{
    const float* preds   = (const float*)d_in[0];
    const float* targets = (const float*)d_in[1];
    // d_in[2] power / d_in[3] kernel / d_in[4] area are analytic -- baked in
    float* ws = (float*)d_ws;

    loss_main<<<512, 256, 0, stream>>>(preds, targets, ws);   // 2 blocks/CU exact
    loss_final<<<1, 256, 0, stream>>>(ws, (float*)d_out);
}